// Round 8
// baseline (1975.551 us; speedup 1.0000x reference)
//
#include <hip/hip_runtime.h>
#include <math.h>

// Problem constants
#define Bn   32
#define Hn   112
#define Wn   112
#define Cn   256
#define HWn  (Hn * Wn)      // 12544 spatial positions
#define C4   (Cn / 4)       // 64 float4 per position
#define HIDn 32

// ----- pipelined (per-batch flag) config -----
#define BCH    8                  // batches per chunk: 102.8 MB << 256 MB L3
#define NCHUNK (Bn / BCH)         // 4 chunks
#define NBF    128                // pool blocks per batch
#define POSF   (HWn / NBF)        // 98 positions per block
#define GRIDF  (BCH * NBF)        // 1024 blocks = 4/CU (residency verified R6: occ 49.3%)
#define SYNC_STRIDE 16            // 64B padding between sync words

// ----- fallback (3-kernel) config -----
#define NB1  32
#define POSB (HWn / NB1)          // 392
#define NB3  98
#define POS3 (HWn / NB3)          // 128

#define NEG_INF (-3.402823466e38f)

typedef float f4 __attribute__((ext_vector_type(4)));

// ===========================================================================
// Pipelined kernel: NO grid-wide sync (R6 counters: 8x grid.sync cost ~1100us
// idle; VALUBusy 1.1%, hbm 642 GB/s). Per-batch atomic arrival counter + a
// scale-ready flag replace it. Each block: pool its slice -> arrive ->
// (blk==0: reduce+MLP+publish) -> spin own batch's flag -> scale own slice
// (x slice still cache-hot). Traffic model confirmed in R6: ~0.84 GB HBM.
// Launched cooperatively ONLY for the co-residency guarantee (no grid.sync).
// ===========================================================================
__global__ __launch_bounds__(256, 4) void pipeline_kernel(
    const f4* __restrict__ x4,
    const float* __restrict__ w1,   // [Cn][HIDn]
    const float* __restrict__ b1,   // [HIDn]
    const float* __restrict__ w2,   // [HIDn][Cn]
    const float* __restrict__ b2,   // [Cn]
    f4* __restrict__ out4,
    float* __restrict__ psum,       // [Bn][NBF][Cn]
    float* __restrict__ pmax,       // [Bn][NBF][Cn]
    float* __restrict__ scale,      // [Bn][Cn]
    int* __restrict__ sync)         // cnt[b] at [b*16], flag[b] at [(Bn+b)*16]
{
    const int tid = threadIdx.x;
    const int c4  = tid & 63;        // float4 channel slot
    const int grp = tid >> 6;        // wave id 0..3
    const int bid = blockIdx.x;
    const int q   = bid >> 7;        // batch-in-chunk 0..7
    const int blk = bid & (NBF - 1); // spatial slice 0..127

    __shared__ f4 ls[256];
    __shared__ f4 lm[256];
    __shared__ float avg[Cn];
    __shared__ float mx[Cn];
    __shared__ float h2[2][HIDn];

    for (int c = 0; c < NCHUNK; ++c) {
        const int b = c * BCH + q;
        int* cnt = sync + (size_t)b * SYNC_STRIDE;
        int* flg = sync + (size_t)(Bn + b) * SYNC_STRIDE;

        // ---------------- phase A: pool own 98-position slice ----------------
        {
            const f4* base = x4 + ((size_t)b * HWn + (size_t)blk * POSF) * C4;
            f4 s = {0.f, 0.f, 0.f, 0.f};
            f4 m = {NEG_INF, NEG_INF, NEG_INF, NEG_INF};
            #pragma unroll 4
            for (int p = grp; p < POSF; p += 4) {
                f4 v = base[(size_t)p * C4 + c4];
                s += v;
                m.x = fmaxf(m.x, v.x); m.y = fmaxf(m.y, v.y);
                m.z = fmaxf(m.z, v.z); m.w = fmaxf(m.w, v.w);
            }
            ls[tid] = s;
            lm[tid] = m;
            __syncthreads();
            if (tid < 64) {
                f4 s0 = ls[tid], s1 = ls[tid + 64], s2 = ls[tid + 128], s3 = ls[tid + 192];
                f4 m0 = lm[tid], m1 = lm[tid + 64], m2 = lm[tid + 128], m3 = lm[tid + 192];
                f4 so = (s0 + s1) + (s2 + s3);
                f4 mo;
                mo.x = fmaxf(fmaxf(m0.x, m1.x), fmaxf(m2.x, m3.x));
                mo.y = fmaxf(fmaxf(m0.y, m1.y), fmaxf(m2.y, m3.y));
                mo.z = fmaxf(fmaxf(m0.z, m1.z), fmaxf(m2.z, m3.z));
                mo.w = fmaxf(fmaxf(m0.w, m1.w), fmaxf(m2.w, m3.w));
                f4* ps4 = (f4*)(psum + ((size_t)b * NBF + blk) * Cn);
                f4* pm4 = (f4*)(pmax + ((size_t)b * NBF + blk) * Cn);
                ps4[tid] = so;   // normal stores: re-read within microseconds
                pm4[tid] = mo;
            }
            __syncthreads();     // compiler drains vmem before s_barrier -> stores issued
            if (tid == 0) {
                __threadfence(); // agent-scope release of the partial rows
                __hip_atomic_fetch_add(cnt, 1, __ATOMIC_RELEASE, __HIP_MEMORY_SCOPE_AGENT);
            }
        }

        // ------- phase B (designated reducer = blk 0): reduce + MLP -------
        if (blk == 0) {
            if (tid == 0) {
                while (__hip_atomic_load(cnt, __ATOMIC_ACQUIRE, __HIP_MEMORY_SCOPE_AGENT) < NBF)
                    __builtin_amdgcn_s_sleep(32);
            }
            __syncthreads();
            __threadfence();     // acquire side: invalidate stale cached lines
            float ssum = 0.f, smax = NEG_INF;
            #pragma unroll 4
            for (int k = 0; k < NBF; ++k) {
                ssum += psum[((size_t)b * NBF + k) * Cn + tid];
                smax  = fmaxf(smax, pmax[((size_t)b * NBF + k) * Cn + tid]);
            }
            avg[tid] = ssum * (1.0f / (float)HWn);
            mx[tid]  = smax;
            __syncthreads();
            if (tid < 64) {
                const int j = tid & 31;
                const int which = tid >> 5;          // 0 = avg, 1 = max
                const float* pool = which ? mx : avg;
                float acc = b1[j];
                #pragma unroll 4
                for (int cc = 0; cc < Cn; ++cc)
                    acc += pool[cc] * w1[cc * HIDn + j];
                h2[which][j] = fmaxf(acc, 0.f);      // relu
            }
            __syncthreads();
            // sigmoid(mlp(avg)+mlp(max)): second layer linear -> b2 twice
            float acc = 2.0f * b2[tid];
            #pragma unroll
            for (int j = 0; j < HIDn; ++j)
                acc += (h2[0][j] + h2[1][j]) * w2[j * Cn + tid];
            scale[(size_t)b * Cn + tid] = 1.0f / (1.0f + expf(-acc));
            __syncthreads();     // drain scale stores
            if (tid == 0) {
                __threadfence();
                __hip_atomic_store(flg, 1, __ATOMIC_RELEASE, __HIP_MEMORY_SCOPE_AGENT);
            }
        }

        // ---------------- wait for this batch's scale ----------------
        if (tid == 0) {
            while (__hip_atomic_load(flg, __ATOMIC_ACQUIRE, __HIP_MEMORY_SCOPE_AGENT) == 0)
                __builtin_amdgcn_s_sleep(32);
        }
        __syncthreads();
        // coherent read of the 4 scale values this thread needs
        const float* sb = scale + (size_t)b * Cn + 4 * c4;
        f4 sc;
        sc.x = __hip_atomic_load(sb + 0, __ATOMIC_RELAXED, __HIP_MEMORY_SCOPE_AGENT);
        sc.y = __hip_atomic_load(sb + 1, __ATOMIC_RELAXED, __HIP_MEMORY_SCOPE_AGENT);
        sc.z = __hip_atomic_load(sb + 2, __ATOMIC_RELAXED, __HIP_MEMORY_SCOPE_AGENT);
        sc.w = __hip_atomic_load(sb + 3, __ATOMIC_RELAXED, __HIP_MEMORY_SCOPE_AGENT);

        // ------- phase C: scale own slice (x slice cache-hot from phase A) -------
        {
            const size_t base = ((size_t)b * HWn + (size_t)blk * POSF) * C4;
            #pragma unroll 4
            for (int p = grp; p < POSF; p += 4) {
                const size_t idx = base + (size_t)p * C4 + c4;
                f4 v = x4[idx];
                v *= sc;
                __builtin_nontemporal_store(v, &out4[idx]);
            }
        }
        // next chunk uses distinct psum/pmax/cnt/flag slots -> no WAR hazard
    }
}

// ===========================================================================
// Fallback path (verified 3-kernel pipeline, 743 us) — used if ws too small
// or cooperative launch refused.
// ===========================================================================
__global__ __launch_bounds__(256) void pool_kernel(
    const f4* __restrict__ x4,
    float* __restrict__ psum,   // [Bn][NB1][Cn]
    float* __restrict__ pmax)   // [Bn][NB1][Cn]
{
    const int b   = blockIdx.y;
    const int blk = blockIdx.x;
    const int tid = threadIdx.x;
    const int c4  = tid & 63;
    const int grp = tid >> 6;

    const f4* base = x4 + ((size_t)b * HWn + (size_t)blk * POSB) * C4;

    f4 s = {0.f, 0.f, 0.f, 0.f};
    f4 m = {NEG_INF, NEG_INF, NEG_INF, NEG_INF};

    #pragma unroll 2
    for (int p = grp; p < POSB; p += 4) {
        f4 v = base[(size_t)p * C4 + c4];
        s += v;
        m.x = fmaxf(m.x, v.x); m.y = fmaxf(m.y, v.y);
        m.z = fmaxf(m.z, v.z); m.w = fmaxf(m.w, v.w);
    }

    __shared__ f4 ls[256];
    __shared__ f4 lm[256];
    ls[tid] = s;
    lm[tid] = m;
    __syncthreads();

    if (tid < 64) {
        f4 s0 = ls[tid], s1 = ls[tid + 64], s2 = ls[tid + 128], s3 = ls[tid + 192];
        f4 m0 = lm[tid], m1 = lm[tid + 64], m2 = lm[tid + 128], m3 = lm[tid + 192];
        f4 so = (s0 + s1) + (s2 + s3);
        f4 mo;
        mo.x = fmaxf(fmaxf(m0.x, m1.x), fmaxf(m2.x, m3.x));
        mo.y = fmaxf(fmaxf(m0.y, m1.y), fmaxf(m2.y, m3.y));
        mo.z = fmaxf(fmaxf(m0.z, m1.z), fmaxf(m2.z, m3.z));
        mo.w = fmaxf(fmaxf(m0.w, m1.w), fmaxf(m2.w, m3.w));
        f4* ps4 = (f4*)(psum + ((size_t)b * NB1 + blk) * Cn);
        f4* pm4 = (f4*)(pmax + ((size_t)b * NB1 + blk) * Cn);
        __builtin_nontemporal_store(so, &ps4[tid]);
        __builtin_nontemporal_store(mo, &pm4[tid]);
    }
}

__global__ __launch_bounds__(256) void mlp_kernel(
    const float* __restrict__ psum,
    const float* __restrict__ pmax,
    const float* __restrict__ w1,
    const float* __restrict__ b1,
    const float* __restrict__ w2,
    const float* __restrict__ b2,
    float* __restrict__ scale)
{
    const int b   = blockIdx.x;
    const int tid = threadIdx.x;

    __shared__ float avg[Cn];
    __shared__ float mx[Cn];
    __shared__ float h2[2][HIDn];

    float s = 0.f;
    float m = NEG_INF;
    for (int k = 0; k < NB1; ++k) {
        s += psum[((size_t)b * NB1 + k) * Cn + tid];
        m = fmaxf(m, pmax[((size_t)b * NB1 + k) * Cn + tid]);
    }
    avg[tid] = s * (1.0f / (float)HWn);
    mx[tid]  = m;
    __syncthreads();

    if (tid < 64) {
        const int j = tid & 31;
        const int which = tid >> 5;
        const float* pool = which ? mx : avg;
        float acc = b1[j];
        for (int c = 0; c < Cn; ++c)
            acc += pool[c] * w1[c * HIDn + j];
        h2[which][j] = fmaxf(acc, 0.f);
    }
    __syncthreads();

    float acc = 2.0f * b2[tid];
    for (int j = 0; j < HIDn; ++j)
        acc += (h2[0][j] + h2[1][j]) * w2[j * Cn + tid];
    scale[(size_t)b * Cn + tid] = 1.0f / (1.0f + expf(-acc));
}

__global__ __launch_bounds__(256) void scale_kernel(
    const f4* __restrict__ x4,
    const float* __restrict__ scale,
    f4* __restrict__ out4)
{
    const int b   = (Bn - 1)  - (int)blockIdx.y;
    const int blk = (NB3 - 1) - (int)blockIdx.x;
    const int tid = threadIdx.x;
    const int c4  = tid & 63;
    const int grp = tid >> 6;

    const f4 sc = ((const f4*)(scale + (size_t)b * Cn))[c4];
    const size_t base = ((size_t)b * HWn + (size_t)blk * POS3) * C4;

    #pragma unroll 4
    for (int p = grp; p < POS3; p += 4) {
        const size_t idx = base + (size_t)p * C4 + c4;
        f4 v = x4[idx];
        v *= sc;
        __builtin_nontemporal_store(v, &out4[idx]);
    }
}

extern "C" void kernel_launch(void* const* d_in, const int* in_sizes, int n_in,
                              void* d_out, int out_size, void* d_ws, size_t ws_size,
                              hipStream_t stream) {
    const float* x  = (const float*)d_in[0];
    const float* w1 = (const float*)d_in[1];
    const float* b1 = (const float*)d_in[2];
    const float* w2 = (const float*)d_in[3];
    const float* b2 = (const float*)d_in[4];
    float* out = (float*)d_out;

    // ws layout: psum[Bn*NBF*Cn] | pmax[Bn*NBF*Cn] | scale[Bn*Cn] | sync[2*Bn*16]
    const size_t fcnt = (size_t)2 * Bn * NBF * Cn + (size_t)Bn * Cn;
    const size_t need = fcnt * sizeof(float) + (size_t)2 * Bn * SYNC_STRIDE * sizeof(int);
    if (ws_size >= need) {
        float* psum  = (float*)d_ws;
        float* pmax  = psum + (size_t)Bn * NBF * Cn;
        float* scale = pmax + (size_t)Bn * NBF * Cn;
        int*   syncw = (int*)(scale + (size_t)Bn * Cn);

        hipMemsetAsync(syncw, 0, (size_t)2 * Bn * SYNC_STRIDE * sizeof(int), stream);

        const f4* x4v = (const f4*)x;
        f4* out4v = (f4*)out;
        void* args[] = {(void*)&x4v, (void*)&w1, (void*)&b1, (void*)&w2, (void*)&b2,
                        (void*)&out4v, (void*)&psum, (void*)&pmax, (void*)&scale,
                        (void*)&syncw};
        // cooperative launch ONLY for the co-residency guarantee (no grid.sync
        // inside) — spin-waits require all 1024 blocks resident (verified R6).
        hipError_t err = hipLaunchCooperativeKernel((const void*)pipeline_kernel,
                                                    dim3(GRIDF), dim3(256),
                                                    args, 0, stream);
        if (err == hipSuccess) return;
        (void)hipGetLastError();   // clear sticky error, fall through
    }

    // ---- fallback: verified 3-kernel path ----
    float* psum  = (float*)d_ws;
    float* pmax  = psum + (size_t)Bn * NB1 * Cn;
    float* scale = pmax + (size_t)Bn * NB1 * Cn;

    pool_kernel<<<dim3(NB1, Bn), 256, 0, stream>>>((const f4*)x, psum, pmax);
    mlp_kernel<<<Bn, 256, 0, stream>>>(psum, pmax, w1, b1, w2, b2, scale);
    scale_kernel<<<dim3(NB3, Bn), 256, 0, stream>>>((const f4*)x, scale, (f4*)out);
}

// Round 15
// 839.651 us; speedup vs baseline: 2.3528x; 2.3528x over previous
//
#include <hip/hip_runtime.h>
#include <math.h>

// Problem constants
#define Bn   32
#define Hn   112
#define Wn   112
#define Cn   256
#define HWn  (Hn * Wn)      // 12544 spatial positions
#define C4   (Cn / 4)       // 64 float4 per position
#define HIDn 32

// ----- chunked multi-launch config -----
// R6/R8 lesson: device-side phase sync (grid.sync OR flag-spin) costs
// 500-800 us idle on this workload; kernel-boundary sync is ~us. Keep the
// CONFIRMED chunked-L3-reuse traffic model (0.84 GB, R6/R8 counters) but
// synchronize via stream-ordered launches: 4 x (pool -> mlp -> scale).
#define BCH    8                  // batches per chunk: 102.8 MB << 256 MB IC
#define NCHUNK (Bn / BCH)         // 4 chunks
#define NBF    128                // pool slices per batch
#define POSF   (HWn / NBF)        // 98 positions per slice

#define NEG_INF (-3.402823466e38f)

typedef float f4 __attribute__((ext_vector_type(4)));

// ---------------------------------------------------------------------------
// pool_chunk: grid (NBF, BCH), block 256. Partial sum/max over one chunk's
// batches. Lane c4 owns 4 channels; wave grp strides spatial positions.
// 64 lanes x 16B = 1KB/wave fully coalesced.
// ---------------------------------------------------------------------------
__global__ __launch_bounds__(256) void pool_chunk(
    const f4* __restrict__ x4,
    float* __restrict__ psum,   // [Bn][NBF][Cn]
    float* __restrict__ pmax,   // [Bn][NBF][Cn]
    int chunk)
{
    const int b   = chunk * BCH + blockIdx.y;
    const int blk = blockIdx.x;
    const int tid = threadIdx.x;
    const int c4  = tid & 63;
    const int grp = tid >> 6;

    const f4* base = x4 + ((size_t)b * HWn + (size_t)blk * POSF) * C4;

    f4 s = {0.f, 0.f, 0.f, 0.f};
    f4 m = {NEG_INF, NEG_INF, NEG_INF, NEG_INF};

    #pragma unroll 4
    for (int p = grp; p < POSF; p += 4) {
        f4 v = base[(size_t)p * C4 + c4];
        s += v;
        m.x = fmaxf(m.x, v.x); m.y = fmaxf(m.y, v.y);
        m.z = fmaxf(m.z, v.z); m.w = fmaxf(m.w, v.w);
    }

    __shared__ f4 ls[256];
    __shared__ f4 lm[256];
    ls[tid] = s;
    lm[tid] = m;
    __syncthreads();

    if (tid < 64) {
        f4 s0 = ls[tid], s1 = ls[tid + 64], s2 = ls[tid + 128], s3 = ls[tid + 192];
        f4 m0 = lm[tid], m1 = lm[tid + 64], m2 = lm[tid + 128], m3 = lm[tid + 192];
        f4 so = (s0 + s1) + (s2 + s3);
        f4 mo;
        mo.x = fmaxf(fmaxf(m0.x, m1.x), fmaxf(m2.x, m3.x));
        mo.y = fmaxf(fmaxf(m0.y, m1.y), fmaxf(m2.y, m3.y));
        mo.z = fmaxf(fmaxf(m0.z, m1.z), fmaxf(m2.z, m3.z));
        mo.w = fmaxf(fmaxf(m0.w, m1.w), fmaxf(m2.w, m3.w));
        f4* ps4 = (f4*)(psum + ((size_t)b * NBF + blk) * Cn);
        f4* pm4 = (f4*)(pmax + ((size_t)b * NBF + blk) * Cn);
        // normal stores: mlp_chunk reads these a few us later -> keep cached
        ps4[tid] = so;
        pm4[tid] = mo;
    }
}

// ---------------------------------------------------------------------------
// mlp_chunk: grid BCH (one block per batch), block 256.
// Reference does sigmoid(mlp(avg) + mlp(max)); second layer linear -> b2
// contributes twice: (h_a + h_m) @ w2 + 2*b2.
// ---------------------------------------------------------------------------
__global__ __launch_bounds__(256) void mlp_chunk(
    const float* __restrict__ psum,
    const float* __restrict__ pmax,
    const float* __restrict__ w1,   // [Cn][HIDn]
    const float* __restrict__ b1,   // [HIDn]
    const float* __restrict__ w2,   // [HIDn][Cn]
    const float* __restrict__ b2,   // [Cn]
    float* __restrict__ scale,      // [Bn][Cn]
    int chunk)
{
    const int b   = chunk * BCH + blockIdx.x;
    const int tid = threadIdx.x;    // channel index

    __shared__ float avg[Cn];
    __shared__ float mx[Cn];
    __shared__ float h2[2][HIDn];

    float s = 0.f;
    float m = NEG_INF;
    #pragma unroll 4
    for (int k = 0; k < NBF; ++k) {
        s += psum[((size_t)b * NBF + k) * Cn + tid];
        m = fmaxf(m, pmax[((size_t)b * NBF + k) * Cn + tid]);
    }
    avg[tid] = s * (1.0f / (float)HWn);
    mx[tid]  = m;
    __syncthreads();

    if (tid < 64) {
        const int j = tid & 31;
        const int which = tid >> 5;              // 0 = avg, 1 = max
        const float* pool = which ? mx : avg;
        float acc = b1[j];
        #pragma unroll 4
        for (int c = 0; c < Cn; ++c)
            acc += pool[c] * w1[c * HIDn + j];
        h2[which][j] = fmaxf(acc, 0.f);          // relu
    }
    __syncthreads();

    float acc = 2.0f * b2[tid];
    #pragma unroll
    for (int j = 0; j < HIDn; ++j)
        acc += (h2[0][j] + h2[1][j]) * w2[j * Cn + tid];
    scale[(size_t)b * Cn + tid] = 1.0f / (1.0f + expf(-acc));
}

// ---------------------------------------------------------------------------
// scale_chunk: grid (NBF, BCH), block 256. Re-reads the chunk's x (still
// Infinity-Cache-resident from pool_chunk: IC is memory-side, persists
// across kernel boundaries) and writes out with NT stores (write-once data,
// keep it from evicting the next chunk's working set).
// ---------------------------------------------------------------------------
__global__ __launch_bounds__(256) void scale_chunk(
    const f4* __restrict__ x4,
    const float* __restrict__ scale,
    f4* __restrict__ out4,
    int chunk)
{
    const int b   = chunk * BCH + blockIdx.y;
    const int blk = blockIdx.x;
    const int tid = threadIdx.x;
    const int c4  = tid & 63;
    const int grp = tid >> 6;

    const f4 sc = ((const f4*)(scale + (size_t)b * Cn))[c4];
    const size_t base = ((size_t)b * HWn + (size_t)blk * POSF) * C4;

    #pragma unroll 4
    for (int p = grp; p < POSF; p += 4) {
        const size_t idx = base + (size_t)p * C4 + c4;
        f4 v = x4[idx];
        v *= sc;
        __builtin_nontemporal_store(v, &out4[idx]);
    }
}

extern "C" void kernel_launch(void* const* d_in, const int* in_sizes, int n_in,
                              void* d_out, int out_size, void* d_ws, size_t ws_size,
                              hipStream_t stream) {
    const float* x  = (const float*)d_in[0];
    const float* w1 = (const float*)d_in[1];
    const float* b1 = (const float*)d_in[2];
    const float* w2 = (const float*)d_in[3];
    const float* b2 = (const float*)d_in[4];
    float* out = (float*)d_out;

    // ws layout: psum[Bn*NBF*Cn] | pmax[Bn*NBF*Cn] | scale[Bn*Cn]  (~8.03 MB)
    float* psum  = (float*)d_ws;
    float* pmax  = psum + (size_t)Bn * NBF * Cn;
    float* scale = pmax + (size_t)Bn * NBF * Cn;

    const f4* x4v = (const f4*)x;
    f4* out4v = (f4*)out;

    // 4 x (pool -> mlp -> scale): kernel boundaries ARE the phase sync
    // (command-processor barrier, ~us — vs 500-800 us for device-side sync,
    // measured R6/R8). scale(c) runs while chunk c (102.8 MB) is IC-resident.
    for (int c = 0; c < NCHUNK; ++c) {
        pool_chunk<<<dim3(NBF, BCH), 256, 0, stream>>>(x4v, psum, pmax, c);
        mlp_chunk<<<BCH, 256, 0, stream>>>(psum, pmax, w1, b1, w2, b2, scale, c);
        scale_chunk<<<dim3(NBF, BCH), 256, 0, stream>>>(x4v, scale, out4v, c);
    }
}

// Round 19
// 823.397 us; speedup vs baseline: 2.3993x; 1.0197x over previous
//
#include <hip/hip_runtime.h>
#include <math.h>

// Problem constants
#define Bn   32
#define Hn   112
#define Wn   112
#define Cn   256
#define HWn  (Hn * Wn)      // 12544 spatial positions
#define C4   (Cn / 4)       // 64 float4 per position
#define HIDn 32

#define NB1  32              // pool chunks per batch
#define POSB (HWn / NB1)     // 392 positions per pool block
#define NB3  98              // scale chunks per batch
#define POS3 (HWn / NB3)     // 128 positions per scale block
#define CNT_STRIDE 16        // 64B padding between per-batch counters

#define NEG_INF (-3.402823466e38f)

typedef float f4 __attribute__((ext_vector_type(4)));

// ---------------------------------------------------------------------------
// Kernel 1: pool + fused MLP via last-block-done.
// grid (NB1, Bn), block 256. Each block pools its 392-position slice exactly
// as the verified 743us baseline. The LAST block to finish a batch (atomic
// arrival counter -- no spinning, unlike R8's 1570us flag-spin) additionally
// reduces the 32 partials and computes sigmoid(mlp(avg)+mlp(max)).
// R15 lesson: launch count/bubbles cost ~100us across 12 launches; this
// removes one launch AND the 8-block mlp kernel's pipeline bubble.
// ---------------------------------------------------------------------------
__global__ __launch_bounds__(256) void pool_mlp_kernel(
    const f4* __restrict__ x4,
    const float* __restrict__ w1,   // [Cn][HIDn]
    const float* __restrict__ b1,   // [HIDn]
    const float* __restrict__ w2,   // [HIDn][Cn]
    const float* __restrict__ b2,   // [Cn]
    float* __restrict__ psum,       // [Bn][NB1][Cn]
    float* __restrict__ pmax,       // [Bn][NB1][Cn]
    float* __restrict__ scale,      // [Bn][Cn]
    int* __restrict__ cnt)          // [Bn] arrival counters (64B-strided)
{
    const int b   = blockIdx.y;
    const int blk = blockIdx.x;
    const int tid = threadIdx.x;
    const int c4  = tid & 63;
    const int grp = tid >> 6;   // 0..3

    // ---------------- pool own slice (identical math to baseline) ----------
    const f4* base = x4 + ((size_t)b * HWn + (size_t)blk * POSB) * C4;

    f4 s = {0.f, 0.f, 0.f, 0.f};
    f4 m = {NEG_INF, NEG_INF, NEG_INF, NEG_INF};

    #pragma unroll 2
    for (int p = grp; p < POSB; p += 4) {
        f4 v = base[(size_t)p * C4 + c4];
        s += v;
        m.x = fmaxf(m.x, v.x); m.y = fmaxf(m.y, v.y);
        m.z = fmaxf(m.z, v.z); m.w = fmaxf(m.w, v.w);
    }

    __shared__ f4 ls[256];
    __shared__ f4 lm[256];
    ls[tid] = s;
    lm[tid] = m;
    __syncthreads();

    if (tid < 64) {
        f4 s0 = ls[tid], s1 = ls[tid + 64], s2 = ls[tid + 128], s3 = ls[tid + 192];
        f4 m0 = lm[tid], m1 = lm[tid + 64], m2 = lm[tid + 128], m3 = lm[tid + 192];
        f4 so = (s0 + s1) + (s2 + s3);
        f4 mo;
        mo.x = fmaxf(fmaxf(m0.x, m1.x), fmaxf(m2.x, m3.x));
        mo.y = fmaxf(fmaxf(m0.y, m1.y), fmaxf(m2.y, m3.y));
        mo.z = fmaxf(fmaxf(m0.z, m1.z), fmaxf(m2.z, m3.z));
        mo.w = fmaxf(fmaxf(m0.w, m1.w), fmaxf(m2.w, m3.w));
        f4* ps4 = (f4*)(psum + ((size_t)b * NB1 + blk) * Cn);
        f4* pm4 = (f4*)(pmax + ((size_t)b * NB1 + blk) * Cn);
        ps4[tid] = so;          // normal stores: re-read within us by last block
        pm4[tid] = mo;
    }

    // ---------------- last-block-done arrival --------------------------------
    __shared__ int isLast;
    __syncthreads();            // drains vmem (compiler emits vmcnt(0) before
                                // s_barrier) -> partial stores complete
    if (tid == 0) {
        __threadfence();        // release partials device-wide
        int old = __hip_atomic_fetch_add(cnt + (size_t)b * CNT_STRIDE, 1,
                                         __ATOMIC_ACQ_REL, __HIP_MEMORY_SCOPE_AGENT);
        isLast = (old == NB1 - 1);
    }
    __syncthreads();
    if (!isLast) return;

    // ---------------- last block: finish reduce + MLP + sigmoid -------------
    __threadfence();            // acquire side: see other blocks' partials
    __shared__ float avg[Cn];
    __shared__ float mx[Cn];
    __shared__ float h2[2][HIDn];

    float ssum = 0.f;
    float smax = NEG_INF;
    #pragma unroll 4
    for (int k = 0; k < NB1; ++k) {
        ssum += psum[((size_t)b * NB1 + k) * Cn + tid];
        smax  = fmaxf(smax, pmax[((size_t)b * NB1 + k) * Cn + tid]);
    }
    avg[tid] = ssum * (1.0f / (float)HWn);
    mx[tid]  = smax;
    __syncthreads();

    if (tid < 64) {
        const int j = tid & 31;
        const int which = tid >> 5;              // 0 = avg, 1 = max
        const float* pool = which ? mx : avg;
        float acc = b1[j];
        #pragma unroll 4
        for (int c = 0; c < Cn; ++c)
            acc += pool[c] * w1[c * HIDn + j];
        h2[which][j] = fmaxf(acc, 0.f);          // relu
    }
    __syncthreads();

    // sigmoid(mlp(avg)+mlp(max)): second layer linear -> b2 contributes twice
    float acc = 2.0f * b2[tid];
    #pragma unroll
    for (int j = 0; j < HIDn; ++j)
        acc += (h2[0][j] + h2[1][j]) * w2[j * Cn + tid];
    scale[(size_t)b * Cn + tid] = 1.0f / (1.0f + expf(-acc));
}

// ---------------------------------------------------------------------------
// Kernel 2: out = x * scale[b,c]. grid (NB3, Bn), block 256, DESCENDING
// order: pool streamed x ascending, so the high addresses are IC-resident —
// start there (R1: -16us vs ascending). NT stores: out is write-once.
// ---------------------------------------------------------------------------
__global__ __launch_bounds__(256) void scale_kernel(
    const f4* __restrict__ x4,
    const float* __restrict__ scale,
    f4* __restrict__ out4)
{
    const int b   = (Bn - 1)  - (int)blockIdx.y;
    const int blk = (NB3 - 1) - (int)blockIdx.x;
    const int tid = threadIdx.x;
    const int c4  = tid & 63;
    const int grp = tid >> 6;

    const f4 sc = ((const f4*)(scale + (size_t)b * Cn))[c4];
    const size_t base = ((size_t)b * HWn + (size_t)blk * POS3) * C4;

    #pragma unroll 4
    for (int p = grp; p < POS3; p += 4) {
        const size_t idx = base + (size_t)p * C4 + c4;
        f4 v = x4[idx];
        v *= sc;
        __builtin_nontemporal_store(v, &out4[idx]);
    }
}

extern "C" void kernel_launch(void* const* d_in, const int* in_sizes, int n_in,
                              void* d_out, int out_size, void* d_ws, size_t ws_size,
                              hipStream_t stream) {
    const float* x  = (const float*)d_in[0];
    const float* w1 = (const float*)d_in[1];
    const float* b1 = (const float*)d_in[2];
    const float* w2 = (const float*)d_in[3];
    const float* b2 = (const float*)d_in[4];
    float* out = (float*)d_out;

    // ws layout: psum[Bn*NB1*Cn] | pmax[Bn*NB1*Cn] | scale[Bn*Cn] | cnt[Bn*16]
    float* psum  = (float*)d_ws;
    float* pmax  = psum + (size_t)Bn * NB1 * Cn;
    float* scale = pmax + (size_t)Bn * NB1 * Cn;
    int*   cnt   = (int*)(scale + (size_t)Bn * Cn);

    // zero the arrival counters (stream-ordered, graph-capture-safe)
    hipMemsetAsync(cnt, 0, (size_t)Bn * CNT_STRIDE * sizeof(int), stream);

    pool_mlp_kernel<<<dim3(NB1, Bn), 256, 0, stream>>>(
        (const f4*)x, w1, b1, w2, b2, psum, pmax, scale, cnt);
    scale_kernel<<<dim3(NB3, Bn), 256, 0, stream>>>(
        (const f4*)x, scale, (f4*)out);
}